// Round 4
// baseline (367.120 us; speedup 1.0000x reference)
//
#include <hip/hip_runtime.h>
#include <math.h>

#define BB   2
#define CFI  32
#define NN   36864          // 192*192
#define NUMM 16

// ---- workspace float-offset layout -----------------------------------------
#define OFF_W1A   0        // [32][32] W1 cols 0..31  (folded with inv1)
#define OFF_W1B   1024     // [32][32] W1 cols 32..63 (folded)
#define OFF_W1P   2048     // [32]     W1 col 64 (Pf term, folded)
#define OFF_W1O0  2080     // [32]     W1 col 65 (folded)
#define OFF_W1O1  2112     // [32]     W1 col 66 (folded)
#define OFF_BETA1 2144     // [32]
#define OFF_W2    2176     // [32][32] folded
#define OFF_BETA2 3200
#define OFF_W3    3232
#define OFF_BETA3 4256
#define OFF_W4    4288
#define OFF_BETA4 5312
#define OFF_WCA   5344     // [32] Wc row 0 (alpha)
#define OFF_WCB   5376     // [32] Wc row 1 (beta)
#define OFF_WCO   5408     // [32] Wc row 2 (omega)
#define OFF_BC    5440     // [3]
#define OFF_Y     6144     // [B*N][32] point-major, beta1 folded in
#define ZOFS      (BB*NN*CFI)           // Z offset inside wsYZ region
// wsYZ = ws + OFF_Y;  Y at wsYZ[0..], Z at wsYZ[ZOFS..]

// Branch-free erf-based gelu. A&S 7.1.26: |eps_abs(erf)| <= 1.5e-7.
static __device__ __forceinline__ float gelu_fast(float x) {
    const float s  = x * 0.70710678118654752f;      // x / sqrt(2)
    const float ax = fabsf(s);
    const float t  = __builtin_amdgcn_rcpf(fmaf(0.3275911f, ax, 1.0f));
    float p = fmaf(1.061405429f, t, -1.453152027f);
    p = fmaf(p, t, 1.421413741f);
    p = fmaf(p, t, -0.284496736f);
    p = fmaf(p, t, 0.254829592f);
    p = p * t;
    const float e  = __expf(-s * s);
    float er = fmaf(-p, e, 1.0f);                   // erf(|s|)
    er = copysignf(er, s);
    return 0.5f * x * (1.0f + er);
}

// ---- kernel 0: fold BN into weights, write folded params to ws -------------
__global__ void fold_kernel(
    const float* __restrict__ W1, const float* __restrict__ g1, const float* __restrict__ b1, const float* __restrict__ m1, const float* __restrict__ v1,
    const float* __restrict__ W2, const float* __restrict__ g2, const float* __restrict__ b2, const float* __restrict__ m2, const float* __restrict__ v2,
    const float* __restrict__ W3, const float* __restrict__ g3, const float* __restrict__ b3, const float* __restrict__ m3, const float* __restrict__ v3,
    const float* __restrict__ W4, const float* __restrict__ g4, const float* __restrict__ b4, const float* __restrict__ m4, const float* __restrict__ v4,
    const float* __restrict__ Wc, const float* __restrict__ bc,
    float* ws)
{
    const int t = threadIdx.x;
    for (int i = t; i < 32 * 67; i += 256) {
        int o = i / 67, c = i - o * 67;
        float inv = g1[o] * rsqrtf(v1[o] + 1e-5f);
        float w = W1[i] * inv;
        if (c < 32)       ws[OFF_W1A + o * 32 + c] = w;
        else if (c < 64)  ws[OFF_W1B + o * 32 + (c - 32)] = w;
        else if (c == 64) ws[OFF_W1P + o] = w;
        else if (c == 65) ws[OFF_W1O0 + o] = w;
        else              ws[OFF_W1O1 + o] = w;
    }
    for (int i = t; i < 1024; i += 256) {
        int o = i >> 5;
        ws[OFF_W2 + i] = W2[i] * (g2[o] * rsqrtf(v2[o] + 1e-5f));
        ws[OFF_W3 + i] = W3[i] * (g3[o] * rsqrtf(v3[o] + 1e-5f));
        ws[OFF_W4 + i] = W4[i] * (g4[o] * rsqrtf(v4[o] + 1e-5f));
    }
    if (t < 32) {
        float i1 = g1[t] * rsqrtf(v1[t] + 1e-5f);
        float i2 = g2[t] * rsqrtf(v2[t] + 1e-5f);
        float i3 = g3[t] * rsqrtf(v3[t] + 1e-5f);
        float i4 = g4[t] * rsqrtf(v4[t] + 1e-5f);
        ws[OFF_BETA1 + t] = b1[t] - m1[t] * i1;
        ws[OFF_BETA2 + t] = b2[t] - m2[t] * i2;
        ws[OFF_BETA3 + t] = b3[t] - m3[t] * i3;
        ws[OFF_BETA4 + t] = b4[t] - m4[t] * i4;
        ws[OFF_WCA + t] = Wc[t];
        ws[OFF_WCB + t] = Wc[32 + t];
        ws[OFF_WCO + t] = Wc[64 + t];
    }
    if (t < 3) ws[OFF_BC + t] = bc[t];
}

// ---- kernel A: per-point Y/Z precompute (layer-1 split), 4 slices/point ----
// wsW (weights, read-only) and wsYZ (Y/Z output) are DISJOINT regions of the
// same workspace, passed as separate __restrict__ pointers so the compiler
// can prove no-clobber and emit scalar (s_load) weight reads. Without this
// split (round 3) every weight read was a per-lane VMEM load.
#define YZ_SLICE_BLOCKS ((BB * NN) / 256)   // 288
__launch_bounds__(256)
__global__ void yz_kernel(const float* __restrict__ If, const float* __restrict__ Pf,
                          const float* __restrict__ wsW, float* __restrict__ wsYZ)
{
    const int r = blockIdx.x / YZ_SLICE_BLOCKS;              // 0..3 channel slice
    const int p = (blockIdx.x % YZ_SLICE_BLOCKS) * 256 + threadIdx.x; // 0..B*N-1
    const int b = p / NN, n = p - b * NN;
    const int o0 = r * 8;
    const float* ifp = If + (size_t)b * CFI * NN + n;

    float accY[8], accZ[8];
#pragma unroll
    for (int j = 0; j < 8; j++) { accY[j] = wsW[OFF_BETA1 + o0 + j]; accZ[j] = 0.0f; }

#pragma unroll
    for (int c = 0; c < 32; c++) {
        float v = ifp[(size_t)c * NN];
#pragma unroll
        for (int j = 0; j < 8; j++) {
            accY[j] = fmaf(wsW[OFF_W1A + (o0 + j) * 32 + c], v, accY[j]);
            accZ[j] = fmaf(wsW[OFF_W1B + (o0 + j) * 32 + c], v, accZ[j]);
        }
    }
    float pf = Pf[p];
#pragma unroll
    for (int j = 0; j < 8; j++) accZ[j] = fmaf(wsW[OFF_W1P + o0 + j], pf, accZ[j]);

    float4* yp = (float4*)(wsYZ + (size_t)p * 32 + o0);
    float4* zp = (float4*)(wsYZ + ZOFS + (size_t)p * 32 + o0);
    yp[0] = make_float4(accY[0], accY[1], accY[2], accY[3]);
    yp[1] = make_float4(accY[4], accY[5], accY[6], accY[7]);
    zp[0] = make_float4(accZ[0], accZ[1], accZ[2], accZ[3]);
    zp[1] = make_float4(accZ[4], accZ[5], accZ[6], accZ[7]);
}

// ---- kernel B: main fused MLP + softmax reduction --------------------------
// One thread handles TWO points sharing all weights: (b=0,n) and (b=1,n).
// Doubles independent VALU work per wave against the same scalar-weight-load
// stall stream (round-3 was ~50% latency-stalled at ~2.5 waves/SIMD).
__launch_bounds__(256, 2)
__global__ void main_kernel(const float* __restrict__ Pf, const float* __restrict__ Of,
                            const int* __restrict__ args,
                            const float* __restrict__ ws, float* __restrict__ out)
{
    const int t = blockIdx.x * 256 + threadIdx.x;   // 0 .. NUM*N-1
    const int m = t & 15;
    const int n = t >> 4;                            // 0 .. NN-1

    const int a0 = args[(0 * NUMM + m) * NN + n];
    const int a1 = args[(1 * NUMM + m) * NN + n];
    const float of00 = Of[((0 * 2 + 0) * NUMM + m) * NN + n];
    const float of01 = Of[((0 * 2 + 1) * NUMM + m) * NN + n];
    const float of10 = Of[((1 * 2 + 0) * NUMM + m) * NN + n];
    const float of11 = Of[((1 * 2 + 1) * NUMM + m) * NN + n];
    const float pfg0 = Pf[a0];
    const float pfg1 = Pf[NN + a1];

    const float4* yp0 = (const float4*)(ws + OFF_Y + (size_t)n * 32);
    const float4* yp1 = (const float4*)(ws + OFF_Y + ((size_t)NN + n) * 32);
    const float4* zp0 = (const float4*)(ws + OFF_Y + ZOFS + (size_t)a0 * 32);
    const float4* zp1 = (const float4*)(ws + OFF_Y + ZOFS + ((size_t)NN + a1) * 32);

    float h1a[32], h1b[32];
#pragma unroll
    for (int i = 0; i < 8; i++) {
        float4 y0 = yp0[i], z0 = zp0[i];
        float4 y1 = yp1[i], z1 = zp1[i];
        h1a[4 * i + 0] = y0.x + z0.x;  h1b[4 * i + 0] = y1.x + z1.x;
        h1a[4 * i + 1] = y0.y + z0.y;  h1b[4 * i + 1] = y1.y + z1.y;
        h1a[4 * i + 2] = y0.z + z0.z;  h1b[4 * i + 2] = y1.z + z1.z;
        h1a[4 * i + 3] = y0.w + z0.w;  h1b[4 * i + 3] = y1.w + z1.w;
    }
#pragma unroll
    for (int o = 0; o < 32; o++) {
        float w0 = ws[OFF_W1O0 + o], w1 = ws[OFF_W1O1 + o];
        float pa = fmaf(of01, w1, fmaf(of00, w0, h1a[o]));
        float pb = fmaf(of11, w1, fmaf(of10, w0, h1b[o]));
        h1a[o] = gelu_fast(pa);
        h1b[o] = gelu_fast(pb);
    }

    float h2a[32], h2b[32];
#pragma unroll
    for (int o = 0; o < 32; o++) {
        float beta = ws[OFF_BETA2 + o];
        float acca = beta, accb = beta;
#pragma unroll
        for (int c = 0; c < 32; c++) {
            float w = ws[OFF_W2 + o * 32 + c];
            acca = fmaf(w, h1a[c], acca);
            accb = fmaf(w, h1b[c], accb);
        }
        h2a[o] = gelu_fast(acca);
        h2b[o] = gelu_fast(accb);
    }

    float l3a[32], l3b[32];
#pragma unroll
    for (int o = 0; o < 32; o++) {
        float beta = ws[OFF_BETA3 + o];
        float acca = beta, accb = beta;
#pragma unroll
        for (int c = 0; c < 32; c++) {
            float w = ws[OFF_W3 + o * 32 + c];
            acca = fmaf(w, h2a[c], acca);
            accb = fmaf(w, h2b[c], accb);
        }
        l3a[o] = gelu_fast(acca);
        l3b[o] = gelu_fast(accb);
    }

    float alpha0 = ws[OFF_BC + 0], beta_0 = ws[OFF_BC + 1], omega0 = ws[OFF_BC + 2];
    float alpha1 = alpha0, beta_1 = beta_0, omega1 = omega0;
#pragma unroll
    for (int o = 0; o < 32; o++) {
        float bb = ws[OFF_BETA4 + o];
        float acca = bb, accb = bb;
#pragma unroll
        for (int c = 0; c < 32; c++) {
            float w = ws[OFF_W4 + o * 32 + c];
            acca = fmaf(w, l3a[c], acca);
            accb = fmaf(w, l3b[c], accb);
        }
        float xfa = gelu_fast(h2a[o] + acca);
        float xfb = gelu_fast(h2b[o] + accb);
        float wa = ws[OFF_WCA + o], wb = ws[OFF_WCB + o], wo = ws[OFF_WCO + o];
        alpha0 = fmaf(wa, xfa, alpha0);  alpha1 = fmaf(wa, xfb, alpha1);
        beta_0 = fmaf(wb, xfa, beta_0);  beta_1 = fmaf(wb, xfb, beta_1);
        omega0 = fmaf(wo, xfa, omega0);  omega1 = fmaf(wo, xfb, omega1);
    }

    const float val0 = fmaf(alpha0 + 1.0f, pfg0, beta_0);
    const float val1 = fmaf(alpha1 + 1.0f, pfg1, beta_1);

    // softmax over m within each 16-lane group (lane bits 0..3)
    float mx0 = omega0, mx1 = omega1;
#pragma unroll
    for (int s = 1; s < 16; s <<= 1) {
        mx0 = fmaxf(mx0, __shfl_xor(mx0, s, 64));
        mx1 = fmaxf(mx1, __shfl_xor(mx1, s, 64));
    }
    const float e0 = __expf(omega0 - mx0);
    const float e1 = __expf(omega1 - mx1);
    float S0 = e0, T0 = val0 * e0;
    float S1 = e1, T1 = val1 * e1;
#pragma unroll
    for (int s = 1; s < 16; s <<= 1) {
        S0 += __shfl_xor(S0, s, 64);  T0 += __shfl_xor(T0, s, 64);
        S1 += __shfl_xor(S1, s, 64);  T1 += __shfl_xor(T1, s, 64);
    }
    if (m == 0) {
        out[n]      = T0 / S0;
        out[NN + n] = T1 / S1;
    }
}

// ---- launcher ---------------------------------------------------------------
extern "C" void kernel_launch(void* const* d_in, const int* in_sizes, int n_in,
                              void* d_out, int out_size, void* d_ws, size_t ws_size,
                              hipStream_t stream) {
    const float* If    = (const float*)d_in[0];
    const float* Pf    = (const float*)d_in[1];
    const float* Of    = (const float*)d_in[2];
    const int*   args  = (const int*)d_in[3];
    const float* W1    = (const float*)d_in[4];
    const float* g1    = (const float*)d_in[5];
    const float* b1    = (const float*)d_in[6];
    const float* m1    = (const float*)d_in[7];
    const float* v1    = (const float*)d_in[8];
    const float* W2    = (const float*)d_in[9];
    const float* g2    = (const float*)d_in[10];
    const float* b2    = (const float*)d_in[11];
    const float* m2    = (const float*)d_in[12];
    const float* v2    = (const float*)d_in[13];
    const float* W3    = (const float*)d_in[14];
    const float* g3    = (const float*)d_in[15];
    const float* b3    = (const float*)d_in[16];
    const float* m3    = (const float*)d_in[17];
    const float* v3    = (const float*)d_in[18];
    const float* W4    = (const float*)d_in[19];
    const float* g4    = (const float*)d_in[20];
    const float* b4    = (const float*)d_in[21];
    const float* m4    = (const float*)d_in[22];
    const float* v4    = (const float*)d_in[23];
    const float* Wc    = (const float*)d_in[24];
    const float* bc    = (const float*)d_in[25];

    float* ws = (float*)d_ws;
    float* out = (float*)d_out;

    fold_kernel<<<1, 256, 0, stream>>>(W1, g1, b1, m1, v1,
                                       W2, g2, b2, m2, v2,
                                       W3, g3, b3, m3, v3,
                                       W4, g4, b4, m4, v4,
                                       Wc, bc, ws);

    yz_kernel<<<YZ_SLICE_BLOCKS * 4, 256, 0, stream>>>(If, Pf, ws, ws + OFF_Y);

    main_kernel<<<(NUMM * NN) / 256, 256, 0, stream>>>(Pf, Of, args, ws, out);
}

// Round 5
// 313.779 us; speedup vs baseline: 1.1700x; 1.1700x over previous
//
#include <hip/hip_runtime.h>
#include <math.h>

#define BB   2
#define CFI  32
#define NN   36864          // 192*192
#define NUMM 16

// workspace: Y at ws[0..], Z at ws[ZOFS..]  (point-major [B*N][32] each)
#define ZOFS (BB * NN * CFI)

// Branch-free erf-based gelu. A&S 7.1.26: |eps_abs(erf)| <= 1.5e-7.
static __device__ __forceinline__ float gelu_fast(float x) {
    const float s  = x * 0.70710678118654752f;      // x / sqrt(2)
    const float ax = fabsf(s);
    const float t  = __builtin_amdgcn_rcpf(fmaf(0.3275911f, ax, 1.0f));
    float p = fmaf(1.061405429f, t, -1.453152027f);
    p = fmaf(p, t, 1.421413741f);
    p = fmaf(p, t, -0.284496736f);
    p = fmaf(p, t, 0.254829592f);
    p = p * t;
    const float e  = __expf(-s * s);
    float er = fmaf(-p, e, 1.0f);                   // erf(|s|)
    er = copysignf(er, s);
    return 0.5f * x * (1.0f + er);
}

// ---- kernel A: per-point Y/Z precompute (layer-1 split) --------------------
// Each block stages the BN-folded W1 halves into LDS (weights are then read
// as all-lane-uniform-address float4 broadcasts, overlapping the fma pipe —
// round-3/4's s_load streaming was lgkm-stall-bound). Fold recomputed per
// block from raw params (L2-hot); fold_kernel deleted.
#define YZ_SLICE_BLOCKS ((BB * NN) / 256)   // 288
__global__ __launch_bounds__(256) void yz_kernel(
    const float* __restrict__ If, const float* __restrict__ Pf,
    const float* __restrict__ W1, const float* __restrict__ g1,
    const float* __restrict__ b1, const float* __restrict__ m1,
    const float* __restrict__ v1,
    float* __restrict__ wsYZ)
{
    __shared__ float wy[1024], wz[1024], wp[32], bt1[32];
    for (int i = threadIdx.x; i < 1024; i += 256) {
        int o = i >> 5, c = i & 31;
        float inv = g1[o] * rsqrtf(v1[o] + 1e-5f);
        wy[i] = W1[o * 67 + c]      * inv;
        wz[i] = W1[o * 67 + 32 + c] * inv;
    }
    if (threadIdx.x < 32) {
        int o = threadIdx.x;
        float inv = g1[o] * rsqrtf(v1[o] + 1e-5f);
        wp[o]  = W1[o * 67 + 64] * inv;
        bt1[o] = b1[o] - m1[o] * inv;
    }
    __syncthreads();

    const int r  = blockIdx.x / YZ_SLICE_BLOCKS;                       // 0..3
    const int p  = (blockIdx.x % YZ_SLICE_BLOCKS) * 256 + threadIdx.x; // 0..B*N-1
    const int b  = p / NN, n = p - b * NN;
    const int o0 = r * 8;
    const float* ifp = If + (size_t)b * CFI * NN + n;

    // front-load the 32 coalesced If reads into registers
    float v[32];
#pragma unroll
    for (int c = 0; c < 32; c++) v[c] = ifp[(size_t)c * NN];
    const float pf = Pf[p];

    float accY[8], accZ[8];
#pragma unroll
    for (int j = 0; j < 8; j++) {
        const float4* wyr = (const float4*)&wy[(o0 + j) * 32];
        const float4* wzr = (const float4*)&wz[(o0 + j) * 32];
        float ay = bt1[o0 + j];
        float az = wp[o0 + j] * pf;
#pragma unroll
        for (int c4 = 0; c4 < 8; c4++) {
            float4 a = wyr[c4], z = wzr[c4];
            ay = fmaf(a.x, v[4 * c4 + 0], ay);  az = fmaf(z.x, v[4 * c4 + 0], az);
            ay = fmaf(a.y, v[4 * c4 + 1], ay);  az = fmaf(z.y, v[4 * c4 + 1], az);
            ay = fmaf(a.z, v[4 * c4 + 2], ay);  az = fmaf(z.z, v[4 * c4 + 2], az);
            ay = fmaf(a.w, v[4 * c4 + 3], ay);  az = fmaf(z.w, v[4 * c4 + 3], az);
        }
        accY[j] = ay; accZ[j] = az;
    }

    float4* yp = (float4*)(wsYZ + (size_t)p * 32 + o0);
    float4* zp = (float4*)(wsYZ + ZOFS + (size_t)p * 32 + o0);
    yp[0] = make_float4(accY[0], accY[1], accY[2], accY[3]);
    yp[1] = make_float4(accY[4], accY[5], accY[6], accY[7]);
    zp[0] = make_float4(accZ[0], accZ[1], accZ[2], accZ[3]);
    zp[1] = make_float4(accZ[4], accZ[5], accZ[6], accZ[7]);
}

// ---- kernel B: main fused MLP + softmax reduction --------------------------
// One thread per (b,m,n); lanes 0..15 of each 16-lane group = m 0..15.
// All folded weights staged in LDS per block (~13 KB); weight reads are
// uniform-address float4 broadcasts.
#define LW2  0
#define LW3  1024
#define LW4  2048
#define LB2  3072
#define LB3  3104
#define LB4  3136
#define LO0  3168
#define LO1  3200
#define LCA  3232
#define LCB  3264
#define LCO  3296
#define LBC  3328
#define LSZ  3344

__global__ __launch_bounds__(256) void main_kernel(
    const float* __restrict__ Pf, const float* __restrict__ Of,
    const int* __restrict__ args,
    const float* __restrict__ W1, const float* __restrict__ g1,
    const float* __restrict__ b1, const float* __restrict__ m1,
    const float* __restrict__ v1,
    const float* __restrict__ W2, const float* __restrict__ g2,
    const float* __restrict__ b2, const float* __restrict__ m2,
    const float* __restrict__ v2,
    const float* __restrict__ W3, const float* __restrict__ g3,
    const float* __restrict__ b3, const float* __restrict__ m3,
    const float* __restrict__ v3,
    const float* __restrict__ W4, const float* __restrict__ g4,
    const float* __restrict__ b4, const float* __restrict__ m4,
    const float* __restrict__ v4,
    const float* __restrict__ Wc, const float* __restrict__ bc,
    const float* __restrict__ wsYZ, float* __restrict__ out)
{
    __shared__ float wl[LSZ];
    for (int i = threadIdx.x; i < 1024; i += 256) {
        int o = i >> 5;
        wl[LW2 + i] = W2[i] * (g2[o] * rsqrtf(v2[o] + 1e-5f));
        wl[LW3 + i] = W3[i] * (g3[o] * rsqrtf(v3[o] + 1e-5f));
        wl[LW4 + i] = W4[i] * (g4[o] * rsqrtf(v4[o] + 1e-5f));
    }
    if (threadIdx.x < 32) {
        int o = threadIdx.x;
        float i1 = g1[o] * rsqrtf(v1[o] + 1e-5f);
        wl[LO0 + o] = W1[o * 67 + 65] * i1;
        wl[LO1 + o] = W1[o * 67 + 66] * i1;
        wl[LB2 + o] = b2[o] - m2[o] * (g2[o] * rsqrtf(v2[o] + 1e-5f));
        wl[LB3 + o] = b3[o] - m3[o] * (g3[o] * rsqrtf(v3[o] + 1e-5f));
        wl[LB4 + o] = b4[o] - m4[o] * (g4[o] * rsqrtf(v4[o] + 1e-5f));
        wl[LCA + o] = Wc[o];
        wl[LCB + o] = Wc[32 + o];
        wl[LCO + o] = Wc[64 + o];
    }
    if (threadIdx.x < 3) wl[LBC + threadIdx.x] = bc[threadIdx.x];
    __syncthreads();

    const int t = blockIdx.x * 256 + threadIdx.x;   // 0 .. B*NUM*N-1
    const int m = t & 15;
    const int q = t >> 4;                            // 0 .. B*N-1
    const int b = q / NN, n = q - b * NN;

    const int   a   = args[((b * NUMM) + m) * NN + n];
    const float of0 = Of[(((b * 2 + 0) * NUMM) + m) * NN + n];
    const float of1 = Of[(((b * 2 + 1) * NUMM) + m) * NN + n];
    const float pfg = Pf[b * NN + a];

    const float4* yp = (const float4*)(wsYZ + (size_t)q * 32);
    const float4* zp = (const float4*)(wsYZ + ZOFS + ((size_t)b * NN + a) * 32);

    float h1[32];
#pragma unroll
    for (int i = 0; i < 8; i++) {
        float4 y = yp[i], z = zp[i];
        h1[4 * i + 0] = y.x + z.x;
        h1[4 * i + 1] = y.y + z.y;
        h1[4 * i + 2] = y.z + z.z;
        h1[4 * i + 3] = y.w + z.w;
    }
#pragma unroll
    for (int o = 0; o < 32; o++) {
        float pre = fmaf(of1, wl[LO1 + o], fmaf(of0, wl[LO0 + o], h1[o]));
        h1[o] = gelu_fast(pre);
    }

    float h2[32];
#pragma unroll
    for (int o = 0; o < 32; o++) {
        float acc = wl[LB2 + o];
        const float4* wr = (const float4*)&wl[LW2 + o * 32];
#pragma unroll
        for (int c4 = 0; c4 < 8; c4++) {
            float4 w = wr[c4];
            acc = fmaf(w.x, h1[4 * c4 + 0], acc);
            acc = fmaf(w.y, h1[4 * c4 + 1], acc);
            acc = fmaf(w.z, h1[4 * c4 + 2], acc);
            acc = fmaf(w.w, h1[4 * c4 + 3], acc);
        }
        h2[o] = gelu_fast(acc);
    }

    float l3[32];
#pragma unroll
    for (int o = 0; o < 32; o++) {
        float acc = wl[LB3 + o];
        const float4* wr = (const float4*)&wl[LW3 + o * 32];
#pragma unroll
        for (int c4 = 0; c4 < 8; c4++) {
            float4 w = wr[c4];
            acc = fmaf(w.x, h2[4 * c4 + 0], acc);
            acc = fmaf(w.y, h2[4 * c4 + 1], acc);
            acc = fmaf(w.z, h2[4 * c4 + 2], acc);
            acc = fmaf(w.w, h2[4 * c4 + 3], acc);
        }
        l3[o] = gelu_fast(acc);
    }

    float alpha = wl[LBC + 0], beta_ = wl[LBC + 1], omega = wl[LBC + 2];
#pragma unroll
    for (int o = 0; o < 32; o++) {
        float acc = wl[LB4 + o];
        const float4* wr = (const float4*)&wl[LW4 + o * 32];
#pragma unroll
        for (int c4 = 0; c4 < 8; c4++) {
            float4 w = wr[c4];
            acc = fmaf(w.x, l3[4 * c4 + 0], acc);
            acc = fmaf(w.y, l3[4 * c4 + 1], acc);
            acc = fmaf(w.z, l3[4 * c4 + 2], acc);
            acc = fmaf(w.w, l3[4 * c4 + 3], acc);
        }
        float xf = gelu_fast(h2[o] + acc);
        alpha = fmaf(wl[LCA + o], xf, alpha);
        beta_ = fmaf(wl[LCB + o], xf, beta_);
        omega = fmaf(wl[LCO + o], xf, omega);
    }

    const float val = fmaf(alpha + 1.0f, pfg, beta_);

    // softmax over m within each 16-lane group (lane bits 0..3)
    float mx = omega;
#pragma unroll
    for (int s = 1; s < 16; s <<= 1) mx = fmaxf(mx, __shfl_xor(mx, s, 64));
    const float e = __expf(omega - mx);
    float S = e, T = val * e;
#pragma unroll
    for (int s = 1; s < 16; s <<= 1) {
        S += __shfl_xor(S, s, 64);
        T += __shfl_xor(T, s, 64);
    }
    if (m == 0) out[q] = T / S;
}

// ---- launcher ---------------------------------------------------------------
extern "C" void kernel_launch(void* const* d_in, const int* in_sizes, int n_in,
                              void* d_out, int out_size, void* d_ws, size_t ws_size,
                              hipStream_t stream) {
    const float* If    = (const float*)d_in[0];
    const float* Pf    = (const float*)d_in[1];
    const float* Of    = (const float*)d_in[2];
    const int*   args  = (const int*)d_in[3];
    const float* W1    = (const float*)d_in[4];
    const float* g1    = (const float*)d_in[5];
    const float* b1    = (const float*)d_in[6];
    const float* m1    = (const float*)d_in[7];
    const float* v1    = (const float*)d_in[8];
    const float* W2    = (const float*)d_in[9];
    const float* g2    = (const float*)d_in[10];
    const float* b2    = (const float*)d_in[11];
    const float* m2    = (const float*)d_in[12];
    const float* v2    = (const float*)d_in[13];
    const float* W3    = (const float*)d_in[14];
    const float* g3    = (const float*)d_in[15];
    const float* b3    = (const float*)d_in[16];
    const float* m3    = (const float*)d_in[17];
    const float* v3    = (const float*)d_in[18];
    const float* W4    = (const float*)d_in[19];
    const float* g4    = (const float*)d_in[20];
    const float* b4    = (const float*)d_in[21];
    const float* m4    = (const float*)d_in[22];
    const float* v4    = (const float*)d_in[23];
    const float* Wc    = (const float*)d_in[24];
    const float* bc    = (const float*)d_in[25];

    float* ws  = (float*)d_ws;
    float* out = (float*)d_out;

    yz_kernel<<<YZ_SLICE_BLOCKS * 4, 256, 0, stream>>>(
        If, Pf, W1, g1, b1, m1, v1, ws);

    main_kernel<<<(BB * NUMM * NN) / 256, 256, 0, stream>>>(
        Pf, Of, args,
        W1, g1, b1, m1, v1,
        W2, g2, b2, m2, v2,
        W3, g3, b3, m3, v3,
        W4, g4, b4, m4, v4,
        Wc, bc, ws, out);
}

// Round 6
// 309.399 us; speedup vs baseline: 1.1866x; 1.0142x over previous
//
#include <hip/hip_runtime.h>
#include <math.h>

#define BB   2
#define CFI  32
#define NN   36864          // 192*192
#define NUMM 16

// workspace: Y at ws[0..], Z at ws[ZOFS..]  (point-major [B*N][32] each)
#define ZOFS (BB * NN * CFI)

// Branch-free erf-based gelu, algebraically reduced:
// erf(|s|) ~= 1 - p(t)*e  (A&S 7.1.26, |eps| <= 1.5e-7), s = x/sqrt(2)
// gelu(x) = 0.5 x (1 + sign(x)(1-pe)) = max(x,0) - (sqrt2/2)|s| * p * e
static __device__ __forceinline__ float gelu_fast(float x) {
    const float s  = x * 0.70710678118654752f;
    const float ax = fabsf(s);
    const float t  = __builtin_amdgcn_rcpf(fmaf(0.3275911f, ax, 1.0f));
    float p = fmaf(1.061405429f, t, -1.453152027f);
    p = fmaf(p, t, 1.421413741f);
    p = fmaf(p, t, -0.284496736f);
    p = fmaf(p, t, 0.254829592f);
    p = p * t;
    const float e = __expf(-s * s);
    return fmaf(-(0.70710678118654752f * ax) * p, e, fmaxf(x, 0.0f));
}

// ---- kernel A: per-point Y/Z precompute (layer-1 split) --------------------
// 4 threads per point; slice r in LOW 2 bits of threadIdx so one wave's
// stores tile a contiguous 2 KB region (round 5 had r in blockIdx high bits
// -> every 128B line filled by 4 different blocks -> partial-line RMW).
__global__ __launch_bounds__(256) void yz_kernel(
    const float* __restrict__ If, const float* __restrict__ Pf,
    const float* __restrict__ W1, const float* __restrict__ g1,
    const float* __restrict__ b1, const float* __restrict__ m1,
    const float* __restrict__ v1,
    float* __restrict__ wsYZ)
{
    __shared__ float wy[1024], wz[1024], wp[32], bt1[32];
    for (int i = threadIdx.x; i < 1024; i += 256) {
        int o = i >> 5, c = i & 31;
        float inv = g1[o] * rsqrtf(v1[o] + 1e-5f);
        wy[i] = W1[o * 67 + c]      * inv;
        wz[i] = W1[o * 67 + 32 + c] * inv;
    }
    if (threadIdx.x < 32) {
        int o = threadIdx.x;
        float inv = g1[o] * rsqrtf(v1[o] + 1e-5f);
        wp[o]  = W1[o * 67 + 64] * inv;
        bt1[o] = b1[o] - m1[o] * inv;
    }
    __syncthreads();

    const int r  = threadIdx.x & 3;                          // channel slice
    const int p  = blockIdx.x * 64 + (threadIdx.x >> 2);     // 0..B*N-1
    const int b  = p / NN, n = p - b * NN;
    const int o0 = r * 8;
    const float* ifp = If + (size_t)b * CFI * NN + n;

    float v[32];
#pragma unroll
    for (int c = 0; c < 32; c++) v[c] = ifp[(size_t)c * NN];
    const float pf = Pf[p];

    float accY[8], accZ[8];
#pragma unroll
    for (int j = 0; j < 8; j++) {
        const float4* wyr = (const float4*)&wy[(o0 + j) * 32];
        const float4* wzr = (const float4*)&wz[(o0 + j) * 32];
        float ay = bt1[o0 + j];
        float az = wp[o0 + j] * pf;
#pragma unroll
        for (int c4 = 0; c4 < 8; c4++) {
            float4 a = wyr[c4], z = wzr[c4];
            ay = fmaf(a.x, v[4 * c4 + 0], ay);  az = fmaf(z.x, v[4 * c4 + 0], az);
            ay = fmaf(a.y, v[4 * c4 + 1], ay);  az = fmaf(z.y, v[4 * c4 + 1], az);
            ay = fmaf(a.z, v[4 * c4 + 2], ay);  az = fmaf(z.z, v[4 * c4 + 2], az);
            ay = fmaf(a.w, v[4 * c4 + 3], ay);  az = fmaf(z.w, v[4 * c4 + 3], az);
        }
        accY[j] = ay; accZ[j] = az;
    }

    float4* yp = (float4*)(wsYZ + (size_t)p * 32 + o0);
    float4* zp = (float4*)(wsYZ + ZOFS + (size_t)p * 32 + o0);
    yp[0] = make_float4(accY[0], accY[1], accY[2], accY[3]);
    yp[1] = make_float4(accY[4], accY[5], accY[6], accY[7]);
    zp[0] = make_float4(accZ[0], accZ[1], accZ[2], accZ[3]);
    zp[1] = make_float4(accZ[4], accZ[5], accZ[6], accZ[7]);
}

// ---- kernel B: main fused MLP + softmax reduction --------------------------
// One thread per (b,m,n). __launch_bounds__(256,1): VGPR cap 512 so the
// h2[32]+l3[32] live set stays in architectural VGPRs — round 5's 68-VGPR
// allocation forced AGPR spill-shuttling (v_accvgpr_*), ~2x VALU inflation.
#define LW2  0
#define LW3  1024
#define LW4  2048
#define LB2  3072
#define LB3  3104
#define LB4  3136
#define LO0  3168
#define LO1  3200
#define LCA  3232
#define LCB  3264
#define LCO  3296
#define LBC  3328
#define LSZ  3344

__global__ __launch_bounds__(256, 1) void main_kernel(
    const float* __restrict__ Pf, const float* __restrict__ Of,
    const int* __restrict__ args,
    const float* __restrict__ W1, const float* __restrict__ g1,
    const float* __restrict__ v1,
    const float* __restrict__ W2, const float* __restrict__ g2,
    const float* __restrict__ b2, const float* __restrict__ m2,
    const float* __restrict__ v2,
    const float* __restrict__ W3, const float* __restrict__ g3,
    const float* __restrict__ b3, const float* __restrict__ m3,
    const float* __restrict__ v3,
    const float* __restrict__ W4, const float* __restrict__ g4,
    const float* __restrict__ b4, const float* __restrict__ m4,
    const float* __restrict__ v4,
    const float* __restrict__ Wc, const float* __restrict__ bc,
    const float* __restrict__ wsYZ, float* __restrict__ out)
{
    __shared__ float wl[LSZ];
    for (int i = threadIdx.x; i < 1024; i += 256) {
        int o = i >> 5;
        wl[LW2 + i] = W2[i] * (g2[o] * rsqrtf(v2[o] + 1e-5f));
        wl[LW3 + i] = W3[i] * (g3[o] * rsqrtf(v3[o] + 1e-5f));
        wl[LW4 + i] = W4[i] * (g4[o] * rsqrtf(v4[o] + 1e-5f));
    }
    if (threadIdx.x < 32) {
        int o = threadIdx.x;
        float i1 = g1[o] * rsqrtf(v1[o] + 1e-5f);
        wl[LO0 + o] = W1[o * 67 + 65] * i1;
        wl[LO1 + o] = W1[o * 67 + 66] * i1;
        wl[LB2 + o] = b2[o] - m2[o] * (g2[o] * rsqrtf(v2[o] + 1e-5f));
        wl[LB3 + o] = b3[o] - m3[o] * (g3[o] * rsqrtf(v3[o] + 1e-5f));
        wl[LB4 + o] = b4[o] - m4[o] * (g4[o] * rsqrtf(v4[o] + 1e-5f));
        wl[LCA + o] = Wc[o];
        wl[LCB + o] = Wc[32 + o];
        wl[LCO + o] = Wc[64 + o];
    }
    if (threadIdx.x < 3) wl[LBC + threadIdx.x] = bc[threadIdx.x];
    __syncthreads();

    const int t = blockIdx.x * 256 + threadIdx.x;   // 0 .. B*NUM*N-1
    const int m = t & 15;
    const int q = t >> 4;                            // 0 .. B*N-1
    const int b = q / NN, n = q - b * NN;

    const int   a   = args[((b * NUMM) + m) * NN + n];
    const float of0 = Of[(((b * 2 + 0) * NUMM) + m) * NN + n];
    const float of1 = Of[(((b * 2 + 1) * NUMM) + m) * NN + n];
    const float pfg = Pf[b * NN + a];

    const float4* yp = (const float4*)(wsYZ + (size_t)q * 32);
    const float4* zp = (const float4*)(wsYZ + ZOFS + ((size_t)b * NN + a) * 32);

    float h1[32];
#pragma unroll
    for (int i = 0; i < 8; i++) {
        float4 y = yp[i], z = zp[i];
        h1[4 * i + 0] = y.x + z.x;
        h1[4 * i + 1] = y.y + z.y;
        h1[4 * i + 2] = y.z + z.z;
        h1[4 * i + 3] = y.w + z.w;
    }
#pragma unroll
    for (int o = 0; o < 32; o++) {
        float pre = fmaf(of1, wl[LO1 + o], fmaf(of0, wl[LO0 + o], h1[o]));
        h1[o] = gelu_fast(pre);
    }

    float h2[32];
#pragma unroll
    for (int o = 0; o < 32; o++) {
        float acc = wl[LB2 + o];
        const float4* wr = (const float4*)&wl[LW2 + o * 32];
#pragma unroll
        for (int c4 = 0; c4 < 8; c4++) {
            float4 w = wr[c4];
            acc = fmaf(w.x, h1[4 * c4 + 0], acc);
            acc = fmaf(w.y, h1[4 * c4 + 1], acc);
            acc = fmaf(w.z, h1[4 * c4 + 2], acc);
            acc = fmaf(w.w, h1[4 * c4 + 3], acc);
        }
        h2[o] = gelu_fast(acc);
    }

    float l3[32];
#pragma unroll
    for (int o = 0; o < 32; o++) {
        float acc = wl[LB3 + o];
        const float4* wr = (const float4*)&wl[LW3 + o * 32];
#pragma unroll
        for (int c4 = 0; c4 < 8; c4++) {
            float4 w = wr[c4];
            acc = fmaf(w.x, h2[4 * c4 + 0], acc);
            acc = fmaf(w.y, h2[4 * c4 + 1], acc);
            acc = fmaf(w.z, h2[4 * c4 + 2], acc);
            acc = fmaf(w.w, h2[4 * c4 + 3], acc);
        }
        l3[o] = gelu_fast(acc);
    }

    float alpha = wl[LBC + 0], beta_ = wl[LBC + 1], omega = wl[LBC + 2];
#pragma unroll
    for (int o = 0; o < 32; o++) {
        float acc = wl[LB4 + o];
        const float4* wr = (const float4*)&wl[LW4 + o * 32];
#pragma unroll
        for (int c4 = 0; c4 < 8; c4++) {
            float4 w = wr[c4];
            acc = fmaf(w.x, l3[4 * c4 + 0], acc);
            acc = fmaf(w.y, l3[4 * c4 + 1], acc);
            acc = fmaf(w.z, l3[4 * c4 + 2], acc);
            acc = fmaf(w.w, l3[4 * c4 + 3], acc);
        }
        float xf = gelu_fast(h2[o] + acc);
        alpha = fmaf(wl[LCA + o], xf, alpha);
        beta_ = fmaf(wl[LCB + o], xf, beta_);
        omega = fmaf(wl[LCO + o], xf, omega);
    }

    const float val = fmaf(alpha + 1.0f, pfg, beta_);

    // softmax over m within each 16-lane group (lane bits 0..3)
    float mx = omega;
#pragma unroll
    for (int s = 1; s < 16; s <<= 1) mx = fmaxf(mx, __shfl_xor(mx, s, 64));
    const float e = __expf(omega - mx);
    float S = e, T = val * e;
#pragma unroll
    for (int s = 1; s < 16; s <<= 1) {
        S += __shfl_xor(S, s, 64);
        T += __shfl_xor(T, s, 64);
    }
    if (m == 0) out[q] = T / S;
}

// ---- launcher ---------------------------------------------------------------
extern "C" void kernel_launch(void* const* d_in, const int* in_sizes, int n_in,
                              void* d_out, int out_size, void* d_ws, size_t ws_size,
                              hipStream_t stream) {
    const float* If    = (const float*)d_in[0];
    const float* Pf    = (const float*)d_in[1];
    const float* Of    = (const float*)d_in[2];
    const int*   args  = (const int*)d_in[3];
    const float* W1    = (const float*)d_in[4];
    const float* g1    = (const float*)d_in[5];
    const float* b1    = (const float*)d_in[6];
    const float* m1    = (const float*)d_in[7];
    const float* v1    = (const float*)d_in[8];
    const float* W2    = (const float*)d_in[9];
    const float* g2    = (const float*)d_in[10];
    const float* b2    = (const float*)d_in[11];
    const float* m2    = (const float*)d_in[12];
    const float* v2    = (const float*)d_in[13];
    const float* W3    = (const float*)d_in[14];
    const float* g3    = (const float*)d_in[15];
    const float* b3    = (const float*)d_in[16];
    const float* m3    = (const float*)d_in[17];
    const float* v3    = (const float*)d_in[18];
    const float* W4    = (const float*)d_in[19];
    const float* g4    = (const float*)d_in[20];
    const float* b4    = (const float*)d_in[21];
    const float* m4    = (const float*)d_in[22];
    const float* v4    = (const float*)d_in[23];
    const float* Wc    = (const float*)d_in[24];
    const float* bc    = (const float*)d_in[25];

    float* ws  = (float*)d_ws;
    float* out = (float*)d_out;

    yz_kernel<<<(BB * NN) / 64, 256, 0, stream>>>(
        If, Pf, W1, g1, b1, m1, v1, ws);

    main_kernel<<<(BB * NUMM * NN) / 256, 256, 0, stream>>>(
        Pf, Of, args,
        W1, g1, v1,
        W2, g2, b2, m2, v2,
        W3, g3, b3, m3, v3,
        W4, g4, b4, m4, v4,
        Wc, bc, ws, out);
}